// Round 11
// baseline (179.830 us; speedup 1.0000x reference)
//
#include <hip/hip_runtime.h>
#include <math.h>

// loss = ALPHA * mean(level_w * (softplus(x) - x*t))
//      + BETA  * sum_{b,e} relu(sig(x[b,dst]) - sig(x[b,src])) / (B*N)
// (scatter target of the consistency add is irrelevant to the mean)
//
// R10: K1 rebuilt as loop-streaming (R9's one-shot 16-load batch collapsed
// to VGPR=36 / 1.3 lines in flight / 2.8 TB/s). Now: fixed column per
// thread, 8 row-iterations, 2 float4 loads + 8B h4 store per iteration ->
// compiler pipelines iterations like the 6.3 TB/s copy pattern. P is
// row-major; K2 does the node-major transpose in registers (8 coalesced
// b64 loads -> 4x h8 -> ds_write_b128) then one-b128-per-endpoint gathers.

#define ALPHA_C 1.0f
#define BETA_C  0.5f

constexpr int B = 4096;
constexpr int N = 4096;
constexpr int E = 16384;

typedef _Float16 h4 __attribute__((ext_vector_type(4)));
typedef _Float16 h8 __attribute__((ext_vector_type(8)));

__global__ __launch_bounds__(64) void init_out_kernel(float* out) {
    if (threadIdx.x == 0) out[0] = 0.0f;
}

__device__ __forceinline__ void fast_sig_sp(float x, float& p, float& sp) {
    // q = exp(-|x|) in (0,1]; both sigmoid and softplus from one exp
    float q = __expf(-fabsf(x));
    float d = 1.0f + q;
    float r = __builtin_amdgcn_rcpf(d);     // ~1 ulp approx reciprocal
    p  = (x >= 0.0f) ? r : q * r;           // sigmoid
    sp = fmaxf(x, 0.0f) + __logf(d);        // softplus = max(x,0)+log(1+q)
}

// ---------------- K1: streaming BCE + sigmoid -> P (row-major fp16) ----
constexpr int T1  = 256;
constexpr int G1  = 2048;                       // 8 blocks/CU
constexpr int IT1 = (B * (N / 4)) / (T1 * G1);  // 8 iterations/thread

__global__ __launch_bounds__(T1, 8) void k1_bce_sig(
    const float* __restrict__ outputs,
    const float* __restrict__ targets,
    const float* __restrict__ level_w,
    _Float16*    __restrict__ P,            // [B][N] fp16 row-major
    float*       __restrict__ out)
{
    __shared__ float red[4];
    const int gt = blockIdx.x * T1 + threadIdx.x;   // 0..524287
    const int c  = gt & (N / 4 - 1);        // fixed float4-column
    const int r0 = gt >> 10;                // 0..511 starting row
    const float4* out4 = (const float4*)outputs;
    const float4* tgt4 = (const float4*)targets;
    const float4 w = ((const float4*)level_w)[c];   // hoisted: column fixed
    const float wv[4] = {w.x, w.y, w.z, w.w};
    h4* P4 = (h4*)P;

    float s1 = 0.0f;
#pragma unroll
    for (int s = 0; s < IT1; ++s) {
        const size_t idx = (size_t)(r0 + s * (B / IT1)) * (N / 4) + c;
        const float4 x = out4[idx];         // coalesced 1 KB/wave
        const float4 t = tgt4[idx];
        const float xv[4] = {x.x, x.y, x.z, x.w};
        const float tv[4] = {t.x, t.y, t.z, t.w};
        h4 pv;
#pragma unroll
        for (int k = 0; k < 4; ++k) {
            float p, sp;
            fast_sig_sp(xv[k], p, sp);
            s1 = fmaf(wv[k], sp - xv[k] * tv[k], s1);
            pv[k] = (_Float16)p;
        }
        P4[idx] = pv;                       // coalesced 512 B/wave store
    }

    // block reduce s1 -> one atomic
#pragma unroll
    for (int off = 32; off > 0; off >>= 1) s1 += __shfl_down(s1, off, 64);
    const int wave = threadIdx.x >> 6, lane = threadIdx.x & 63;
    if (lane == 0) red[wave] = s1;
    __syncthreads();
    if (threadIdx.x == 0) {
        float a = red[0] + red[1] + red[2] + red[3];
        atomicAdd(out, ALPHA_C * a / ((float)B * (float)N));
    }
}

// ---------------- K2: transpose-to-LDS + edge gathers ----------------
constexpr int T2 = 1024;
__global__ __launch_bounds__(T2, 2) void k2_edges(
    const _Float16* __restrict__ P,
    const int*      __restrict__ edge_src,
    const int*      __restrict__ edge_dst,
    float*          __restrict__ out)
{
    __shared__ h8 Pl[N];                    // 64 KB node-major: Pl[n][r]
    __shared__ float red[16];

    const int g   = blockIdx.x;             // rows 8g..8g+7
    const int tid = threadIdx.x;            // owns nodes 4tid..4tid+3

    // edge indices first: 8 int4 cached in regs, in flight during fill
    const int4* es4 = (const int4*)edge_src;
    const int4* ed4 = (const int4*)edge_dst;
    int4 sc[4], dc[4];
#pragma unroll
    for (int j = 0; j < 4; ++j) {
        sc[j] = es4[tid + j * T2];
        dc[j] = ed4[tid + j * T2];
    }

    // load 8 row-slices (coalesced b64), register-transpose, store b128
    const h4* Pr = (const h4*)P + (size_t)(8 * g) * (N / 4);
    h4 rowv[8];
#pragma unroll
    for (int r = 0; r < 8; ++r)
        rowv[r] = Pr[(size_t)r * (N / 4) + tid];    // 512 B/wave each
    h8 tp[4];
#pragma unroll
    for (int k = 0; k < 4; ++k) {
#pragma unroll
        for (int r = 0; r < 8; ++r) tp[k][r] = rowv[r][k];
    }
#pragma unroll
    for (int k = 0; k < 4; ++k) Pl[4 * tid + k] = tp[k];  // ds_write_b128
    __syncthreads();

    // gather: ONE ds_read_b128 per endpoint covers 8 rows
    float s2 = 0.0f;
    const h8 zero = {0, 0, 0, 0, 0, 0, 0, 0};
#pragma unroll
    for (int j = 0; j < 4; ++j) {
        h8 acc = zero;                      // <=4 edges: fp16-safe magnitude
        h8 a0 = Pl[sc[j].x], c0 = Pl[dc[j].x];
        h8 a1 = Pl[sc[j].y], c1 = Pl[dc[j].y];
        h8 a2 = Pl[sc[j].z], c2 = Pl[dc[j].z];
        h8 a3 = Pl[sc[j].w], c3 = Pl[dc[j].w];
        acc += __builtin_elementwise_max(c0 - a0, zero);    // v_pk_* fp16
        acc += __builtin_elementwise_max(c1 - a1, zero);
        acc += __builtin_elementwise_max(c2 - a2, zero);
        acc += __builtin_elementwise_max(c3 - a3, zero);
#pragma unroll
        for (int l = 0; l < 8; ++l) s2 += (float)acc[l];    // fp32 flush
    }

    // block reduce s2 -> one atomic
#pragma unroll
    for (int off = 32; off > 0; off >>= 1) s2 += __shfl_down(s2, off, 64);
    const int wave = tid >> 6, lane = tid & 63;
    if (lane == 0) red[wave] = s2;
    __syncthreads();
    if (tid == 0) {
        float c = 0.0f;
#pragma unroll
        for (int i = 0; i < 16; ++i) c += red[i];
        atomicAdd(out, BETA_C * c / ((float)B * (float)N));
    }
}

extern "C" void kernel_launch(void* const* d_in, const int* in_sizes, int n_in,
                              void* d_out, int out_size, void* d_ws, size_t ws_size,
                              hipStream_t stream) {
    const float* outputs = (const float*)d_in[0];
    const float* targets = (const float*)d_in[1];
    const float* level_w = (const float*)d_in[2];
    const int*   edge_src = (const int*)d_in[3];
    const int*   edge_dst = (const int*)d_in[4];
    float* out = (float*)d_out;
    _Float16* P = (_Float16*)d_ws;          // 32 MB scratch

    init_out_kernel<<<1, 64, 0, stream>>>(out);
    k1_bce_sig<<<G1, T1, 0, stream>>>(outputs, targets, level_w, P, out);
    k2_edges<<<B / 8, T2, 0, stream>>>(P, edge_src, edge_dst, out);
}